// Round 2
// baseline (4147.449 us; speedup 1.0000x reference)
//
#include <hip/hip_runtime.h>

// 2D acoustic FDTD, temporally blocked, register-resident bands.
// KT=16 steps/launch, halo=KT. 8 full-width strips x B blocks, 1024 thr.
// Each wave (64 lanes) owns 4 consecutive rows in registers; only band
// top/bottom rows are published to LDS (ping-pong). Lateral neighbors via
// DPP wave_shr:1 / wave_shl:1 (bound_ctrl gives the x-domain-edge zeros).

#define HH 256
#define WW 256
#define KT 16                 // time steps per launch == halo rows
#define SHR 32                // strip interior height
#define NSTRIP (HH / SHR)     // 8
#define NSLOT 16              // row-slots (= waves) per block
#define RPT 4                 // rows per thread (band height)
#define NTH 1024
#define C2SCALE 1.0e-4f       // DT/DX

__device__ __forceinline__ float dpp_west(float v) {
    // lane i <- lane i-1 ; lane 0 <- 0   (wave_shr:1, bound_ctrl:1)
    return __int_as_float(__builtin_amdgcn_mov_dpp(__float_as_int(v), 0x138, 0xf, 0xf, true));
}
__device__ __forceinline__ float dpp_east(float v) {
    // lane i <- lane i+1 ; lane 63 <- 0  (wave_shl:1, bound_ctrl:1)
    return __int_as_float(__builtin_amdgcn_mov_dpp(__float_as_int(v), 0x130, 0xf, 0xf, true));
}

__global__ __launch_bounds__(NTH, 1) void wave_chunk(
    const float* __restrict__ x, const float* __restrict__ vp,
    const int* __restrict__ src_y, const int* __restrict__ src_x,
    const int* __restrict__ rec_y, const int* __restrict__ rec_x,
    float* __restrict__ gcur, float* __restrict__ gprev,
    float* __restrict__ out, int t0, int nsteps, int B, int NR, int init)
{
    __shared__ float bnd[2][NSLOT][2][WW];   // 64 KB ping-pong boundary rows

    const int strip = blockIdx.x;
    const int bb    = blockIdx.y;
    const int y0    = strip * SHR;
    const int lo    = max(0, y0 - KT);
    const int hi    = min(HH, y0 + SHR + KT);
    const int RL    = hi - lo;               // 48 or 64 region rows

    const int tid  = threadIdx.x;
    const int lane = tid & 63;
    const int rs   = tid >> 6;               // wave id == row slot
    const int xg   = lane * 4;
    const int r0   = rs * RPT;
    const int gy0  = lo + r0;

    float4 u[RPT], pv[RPT], c2[RPT];
    const size_t bbase = (size_t)bb * HH * WW;

    // ---- load band (u,pv from global unless init; c2 from vp) ----
    #pragma unroll
    for (int i = 0; i < RPT; ++i) {
        const int r = r0 + i;
        if (r < RL) {
            const int gy = lo + r;
            const size_t gi = bbase + (size_t)gy * WW + xg;
            float4 v = *(const float4*)&vp[gy * WW + xg];
            float4 cc;
            cc.x = v.x * C2SCALE; cc.y = v.y * C2SCALE;
            cc.z = v.z * C2SCALE; cc.w = v.w * C2SCALE;
            cc.x *= cc.x; cc.y *= cc.y; cc.z *= cc.z; cc.w *= cc.w;
            c2[i] = cc;
            if (init) {
                u[i]  = make_float4(0.f, 0.f, 0.f, 0.f);
                pv[i] = make_float4(0.f, 0.f, 0.f, 0.f);
            } else {
                u[i]  = *(const float4*)&gcur[gi];
                pv[i] = *(const float4*)&gprev[gi];
            }
        } else {
            c2[i] = make_float4(0.f, 0.f, 0.f, 0.f);
            u[i]  = make_float4(0.f, 0.f, 0.f, 0.f);
            pv[i] = make_float4(0.f, 0.f, 0.f, 0.f);
        }
    }

    // ---- source ownership (static per launch) ----
    const int sy = src_y[bb];
    const int sx = src_x[bb];
    const int srr = sy - gy0;                        // 0..3 if mine
    const bool mine_src = (sy >= lo) && (sy < hi) &&
                          (srr >= 0) && (srr < RPT) && ((sx >> 2) == lane);
    const int sc = sx & 3;

    // ---- receiver ownership: <=6 static slots per thread ----
    int e0 = 0, e1 = 0, e2 = 0, e3 = 0, e4 = 0, e5 = 0, cnt = 0;
    for (int k = 0; k < NR; ++k) {
        const int ry = rec_y[k];
        if (ry >= y0 && ry < y0 + SHR) {
            const int rr = ry - gy0;
            if (rr >= 0 && rr < RPT) {
                const int rx = rec_x[k];
                if ((rx >> 2) == lane) {
                    const int pk = (k << 4) | (rr << 2) | (rx & 3);
                    if (cnt == 0) e0 = pk; else if (cnt == 1) e1 = pk;
                    else if (cnt == 2) e2 = pk; else if (cnt == 3) e3 = pk;
                    else if (cnt == 4) e4 = pk; else e5 = pk;
                    ++cnt;
                }
            }
        }
    }

    // ---- publish initial boundary rows ----
    *(float4*)&bnd[0][rs][0][xg] = u[0];
    *(float4*)&bnd[0][rs][1][xg] = u[RPT - 1];
    __syncthreads();

    const bool north_zero = (rs == 0);                         // region top (or y=0 edge)
    const bool south_zero = (rs == NSLOT - 1) || (gy0 + RPT - 1 == HH - 1);

    int cur = 0;
    for (int s = 0; s < nsteps; ++s) {
        const int t = t0 + s;
        const float xi = x[t * B + bb];          // uniform; latency hidden by compute

        float4 nin = make_float4(0.f, 0.f, 0.f, 0.f);
        float4 sin4 = make_float4(0.f, 0.f, 0.f, 0.f);
        if (!north_zero) nin  = *(const float4*)&bnd[cur][rs - 1][1][xg];
        if (!south_zero) sin4 = *(const float4*)&bnd[cur][rs + 1][0][xg];

        float4 un[RPT];
        // register-only interior rows first, LDS-dependent rows last
        #pragma unroll
        for (int ii = 0; ii < RPT; ++ii) {
            const int i = (ii == 0) ? 1 : (ii == 1) ? 2 : (ii == 2) ? 0 : 3;
            const float4 c  = u[i];
            const float4 nn = (i == 0) ? nin  : u[i - 1];
            const float4 ss = (i == RPT - 1) ? sin4 : u[i + 1];
            const float wl = dpp_west(c.w);
            const float er = dpp_east(c.x);
            float4 lap;
            lap.x = nn.x + ss.x + wl  + c.y - 4.0f * c.x;
            lap.y = nn.y + ss.y + c.x + c.z - 4.0f * c.y;
            lap.z = nn.z + ss.z + c.y + c.w - 4.0f * c.z;
            lap.w = nn.w + ss.w + c.z + er  - 4.0f * c.w;
            float4 r;
            r.x = 2.0f * c.x - pv[i].x + c2[i].x * lap.x;
            r.y = 2.0f * c.y - pv[i].y + c2[i].y * lap.y;
            r.z = 2.0f * c.z - pv[i].z + c2[i].z * lap.z;
            r.w = 2.0f * c.w - pv[i].w + c2[i].w * lap.w;
            un[i] = r;
        }

        // source injection (compile-time-indexed, single owning thread)
        if (mine_src) {
            if (srr == 0) { if (sc==0) un[0].x+=xi; else if (sc==1) un[0].y+=xi; else if (sc==2) un[0].z+=xi; else un[0].w+=xi; }
            else if (srr == 1) { if (sc==0) un[1].x+=xi; else if (sc==1) un[1].y+=xi; else if (sc==2) un[1].z+=xi; else un[1].w+=xi; }
            else if (srr == 2) { if (sc==0) un[2].x+=xi; else if (sc==1) un[2].y+=xi; else if (sc==2) un[2].z+=xi; else un[2].w+=xi; }
            else               { if (sc==0) un[3].x+=xi; else if (sc==1) un[3].y+=xi; else if (sc==2) un[3].z+=xi; else un[3].w+=xi; }
        }

        #pragma unroll
        for (int i = 0; i < RPT; ++i) { pv[i] = u[i]; u[i] = un[i]; }

        *(float4*)&bnd[cur ^ 1][rs][0][xg] = u[0];
        *(float4*)&bnd[cur ^ 1][rs][1][xg] = u[RPT - 1];

        // receiver emission (rare divergent path, cndmask value select)
        if (cnt > 0) {
            const size_t obase = (size_t)t * B * NR + (size_t)bb * NR;
            #define EMIT(E) { int pk=(E); int rr=(pk>>2)&3; int c=pk&3;             \
                float4 uu = (rr==0)?u[0]:((rr==1)?u[1]:((rr==2)?u[2]:u[3]));        \
                float v = (c==0)?uu.x:((c==1)?uu.y:((c==2)?uu.z:uu.w));             \
                out[obase + (pk>>4)] = v; }
            EMIT(e0);
            if (cnt > 1) { EMIT(e1);
              if (cnt > 2) { EMIT(e2);
                if (cnt > 3) { EMIT(e3);
                  if (cnt > 4) { EMIT(e4);
                    if (cnt > 5) { EMIT(e5); } } } } }
            #undef EMIT
        }

        __syncthreads();
        cur ^= 1;
    }

    // ---- write back interior rows of both time levels ----
    #pragma unroll
    for (int i = 0; i < RPT; ++i) {
        const int r = r0 + i;
        const int gy = lo + r;
        if (r < RL && gy >= y0 && gy < y0 + SHR) {
            const size_t gi = bbase + (size_t)gy * WW + xg;
            *(float4*)&gcur[gi]  = u[i];
            *(float4*)&gprev[gi] = pv[i];
        }
    }
}

extern "C" void kernel_launch(void* const* d_in, const int* in_sizes, int n_in,
                              void* d_out, int out_size, void* d_ws, size_t ws_size,
                              hipStream_t stream) {
    const float* x     = (const float*)d_in[0];
    const float* vp    = (const float*)d_in[1];
    const int* src_y   = (const int*)d_in[2];
    const int* src_x   = (const int*)d_in[3];
    const int* rec_y   = (const int*)d_in[4];
    const int* rec_x   = (const int*)d_in[5];

    const int B  = in_sizes[2];
    const int NR = in_sizes[4];
    const int NT = in_sizes[0] / B;

    float* gcur  = (float*)d_ws;
    float* gprev = gcur + (size_t)B * HH * WW;
    float* outp  = (float*)d_out;

    dim3 grid(NSTRIP, B), block(NTH);
    for (int t0 = 0; t0 < NT; t0 += KT) {
        const int ns = (NT - t0 < KT) ? (NT - t0) : KT;
        wave_chunk<<<grid, block, 0, stream>>>(x, vp, src_y, src_x, rec_y, rec_x,
                                               gcur, gprev, outp, t0, ns, B, NR,
                                               (t0 == 0) ? 1 : 0);
    }
}

// Round 3
// 3942.764 us; speedup vs baseline: 1.0519x; 1.0519x over previous
//
#include <hip/hip_runtime.h>

// 2D acoustic FDTD, temporally blocked, register-resident bands.
// KT=16 steps/launch, halo=KT. 8 full-width strips x B blocks, 1024 thr.
// Each wave (64 lanes) owns 4 consecutive rows in registers; only band
// top/bottom rows are published to LDS (ping-pong). Lateral neighbors via
// DPP wave_shr:1 / wave_shl:1 (bound_ctrl gives the x-domain-edge zeros).
// R3 fix vs R2: __launch_bounds__(1024,4) -> 128-VGPR budget (R2 spilled at
// 64); receiver scan reads LDS-staged coords; x-chunk staged in LDS.

#define HH 256
#define WW 256
#define KT 16                 // time steps per launch == halo rows
#define SHR 32                // strip interior height
#define NSTRIP (HH / SHR)     // 8
#define NSLOT 16              // row-slots (= waves) per block
#define RPT 4                 // rows per thread (band height)
#define NTH 1024
#define C2SCALE 1.0e-4f       // DT/DX
#define NRMAX 128

__device__ __forceinline__ float dpp_west(float v) {
    // lane i <- lane i-1 ; lane 0 <- 0   (wave_shr:1, bound_ctrl:1)
    return __int_as_float(__builtin_amdgcn_mov_dpp(__float_as_int(v), 0x138, 0xf, 0xf, true));
}
__device__ __forceinline__ float dpp_east(float v) {
    // lane i <- lane i+1 ; lane 63 <- 0  (wave_shl:1, bound_ctrl:1)
    return __int_as_float(__builtin_amdgcn_mov_dpp(__float_as_int(v), 0x130, 0xf, 0xf, true));
}

__global__ __launch_bounds__(NTH, 4) void wave_chunk(
    const float* __restrict__ x, const float* __restrict__ vp,
    const int* __restrict__ src_y, const int* __restrict__ src_x,
    const int* __restrict__ rec_y, const int* __restrict__ rec_x,
    float* __restrict__ gcur, float* __restrict__ gprev,
    float* __restrict__ out, int t0, int nsteps, int B, int NR, int init)
{
    __shared__ float bnd[2][NSLOT][2][WW];   // 64 KB ping-pong boundary rows
    __shared__ int   recy_s[NRMAX], recx_s[NRMAX];
    __shared__ float xs[KT];

    const int strip = blockIdx.x;
    const int bb    = blockIdx.y;
    const int y0    = strip * SHR;
    const int lo    = max(0, y0 - KT);
    const int hi    = min(HH, y0 + SHR + KT);
    const int RL    = hi - lo;               // 48 or 64 region rows

    const int tid  = threadIdx.x;
    const int lane = tid & 63;
    const int rs   = tid >> 6;               // wave id == row slot
    const int xg   = lane * 4;
    const int r0   = rs * RPT;
    const int gy0  = lo + r0;

    float4 u[RPT], pv[RPT], c2[RPT];
    const size_t bbase = (size_t)bb * HH * WW;

    // ---- stage receiver coords + source chunk into LDS (coalesced) ----
    if (tid < NR)     { recy_s[tid] = rec_y[tid]; recx_s[tid] = rec_x[tid]; }
    if (tid < nsteps) { xs[tid] = x[(t0 + tid) * B + bb]; }

    // ---- load band (u,pv from global unless init; c2 from vp) ----
    #pragma unroll
    for (int i = 0; i < RPT; ++i) {
        const int r = r0 + i;
        if (r < RL) {
            const int gy = lo + r;
            const size_t gi = bbase + (size_t)gy * WW + xg;
            float4 v = *(const float4*)&vp[gy * WW + xg];
            float4 cc;
            cc.x = v.x * C2SCALE; cc.y = v.y * C2SCALE;
            cc.z = v.z * C2SCALE; cc.w = v.w * C2SCALE;
            cc.x *= cc.x; cc.y *= cc.y; cc.z *= cc.z; cc.w *= cc.w;
            c2[i] = cc;
            if (init) {
                u[i]  = make_float4(0.f, 0.f, 0.f, 0.f);
                pv[i] = make_float4(0.f, 0.f, 0.f, 0.f);
            } else {
                u[i]  = *(const float4*)&gcur[gi];
                pv[i] = *(const float4*)&gprev[gi];
            }
        } else {
            c2[i] = make_float4(0.f, 0.f, 0.f, 0.f);
            u[i]  = make_float4(0.f, 0.f, 0.f, 0.f);
            pv[i] = make_float4(0.f, 0.f, 0.f, 0.f);
        }
    }

    // ---- source ownership (static per launch) ----
    const int sy = src_y[bb];
    const int sx = src_x[bb];
    const int srr = sy - gy0;                        // 0..3 if mine
    const bool mine_src = (sy >= lo) && (sy < hi) &&
                          (srr >= 0) && (srr < RPT) && ((sx >> 2) == lane);
    const int sc = sx & 3;

    // ---- publish initial boundary rows (also fences the LDS staging) ----
    *(float4*)&bnd[0][rs][0][xg] = u[0];
    *(float4*)&bnd[0][rs][1][xg] = u[RPT - 1];
    __syncthreads();

    // ---- receiver ownership: <=6 static slots per thread (LDS scan) ----
    int e0 = 0, e1 = 0, e2 = 0, e3 = 0, e4 = 0, e5 = 0, cnt = 0;
    for (int k = 0; k < NR; ++k) {
        const int ry = recy_s[k];                    // broadcast LDS read
        if (ry >= y0 && ry < y0 + SHR) {
            const int rr = ry - gy0;
            if (rr >= 0 && rr < RPT) {
                const int rx = recx_s[k];
                if ((rx >> 2) == lane) {
                    const int pk = (k << 4) | (rr << 2) | (rx & 3);
                    if (cnt == 0) e0 = pk; else if (cnt == 1) e1 = pk;
                    else if (cnt == 2) e2 = pk; else if (cnt == 3) e3 = pk;
                    else if (cnt == 4) e4 = pk; else e5 = pk;
                    ++cnt;
                }
            }
        }
    }

    const bool north_zero = (rs == 0);                         // region top (or y=0 edge)
    const bool south_zero = (rs == NSLOT - 1) || (gy0 + RPT - 1 == HH - 1);

    int cur = 0;
    for (int s = 0; s < nsteps; ++s) {
        const int t = t0 + s;

        float4 nin = make_float4(0.f, 0.f, 0.f, 0.f);
        float4 sin4 = make_float4(0.f, 0.f, 0.f, 0.f);
        if (!north_zero) nin  = *(const float4*)&bnd[cur][rs - 1][1][xg];
        if (!south_zero) sin4 = *(const float4*)&bnd[cur][rs + 1][0][xg];

        float4 un[RPT];
        // register-only interior rows first, LDS-dependent rows last
        #pragma unroll
        for (int ii = 0; ii < RPT; ++ii) {
            const int i = (ii == 0) ? 1 : (ii == 1) ? 2 : (ii == 2) ? 0 : 3;
            const float4 c  = u[i];
            const float4 nn = (i == 0) ? nin  : u[i - 1];
            const float4 ss = (i == RPT - 1) ? sin4 : u[i + 1];
            const float wl = dpp_west(c.w);
            const float er = dpp_east(c.x);
            float4 lap;
            lap.x = nn.x + ss.x + wl  + c.y - 4.0f * c.x;
            lap.y = nn.y + ss.y + c.x + c.z - 4.0f * c.y;
            lap.z = nn.z + ss.z + c.y + c.w - 4.0f * c.z;
            lap.w = nn.w + ss.w + c.z + er  - 4.0f * c.w;
            float4 r;
            r.x = 2.0f * c.x - pv[i].x + c2[i].x * lap.x;
            r.y = 2.0f * c.y - pv[i].y + c2[i].y * lap.y;
            r.z = 2.0f * c.z - pv[i].z + c2[i].z * lap.z;
            r.w = 2.0f * c.w - pv[i].w + c2[i].w * lap.w;
            un[i] = r;
        }

        // source injection (compile-time-indexed, single owning thread)
        if (mine_src) {
            const float xi = xs[s];
            if (srr == 0) { if (sc==0) un[0].x+=xi; else if (sc==1) un[0].y+=xi; else if (sc==2) un[0].z+=xi; else un[0].w+=xi; }
            else if (srr == 1) { if (sc==0) un[1].x+=xi; else if (sc==1) un[1].y+=xi; else if (sc==2) un[1].z+=xi; else un[1].w+=xi; }
            else if (srr == 2) { if (sc==0) un[2].x+=xi; else if (sc==1) un[2].y+=xi; else if (sc==2) un[2].z+=xi; else un[2].w+=xi; }
            else               { if (sc==0) un[3].x+=xi; else if (sc==1) un[3].y+=xi; else if (sc==2) un[3].z+=xi; else un[3].w+=xi; }
        }

        #pragma unroll
        for (int i = 0; i < RPT; ++i) { pv[i] = u[i]; u[i] = un[i]; }

        *(float4*)&bnd[cur ^ 1][rs][0][xg] = u[0];
        *(float4*)&bnd[cur ^ 1][rs][1][xg] = u[RPT - 1];

        // receiver emission (rare divergent path, cndmask value select)
        if (cnt > 0) {
            const size_t obase = (size_t)t * B * NR + (size_t)bb * NR;
            #define EMIT(E) { int pk=(E); int rr=(pk>>2)&3; int c=pk&3;             \
                float4 uu = (rr==0)?u[0]:((rr==1)?u[1]:((rr==2)?u[2]:u[3]));        \
                float v = (c==0)?uu.x:((c==1)?uu.y:((c==2)?uu.z:uu.w));             \
                out[obase + (pk>>4)] = v; }
            EMIT(e0);
            if (cnt > 1) { EMIT(e1);
              if (cnt > 2) { EMIT(e2);
                if (cnt > 3) { EMIT(e3);
                  if (cnt > 4) { EMIT(e4);
                    if (cnt > 5) { EMIT(e5); } } } } }
            #undef EMIT
        }

        __syncthreads();
        cur ^= 1;
    }

    // ---- write back interior rows of both time levels ----
    #pragma unroll
    for (int i = 0; i < RPT; ++i) {
        const int r = r0 + i;
        const int gy = lo + r;
        if (r < RL && gy >= y0 && gy < y0 + SHR) {
            const size_t gi = bbase + (size_t)gy * WW + xg;
            *(float4*)&gcur[gi]  = u[i];
            *(float4*)&gprev[gi] = pv[i];
        }
    }
}

extern "C" void kernel_launch(void* const* d_in, const int* in_sizes, int n_in,
                              void* d_out, int out_size, void* d_ws, size_t ws_size,
                              hipStream_t stream) {
    const float* x     = (const float*)d_in[0];
    const float* vp    = (const float*)d_in[1];
    const int* src_y   = (const int*)d_in[2];
    const int* src_x   = (const int*)d_in[3];
    const int* rec_y   = (const int*)d_in[4];
    const int* rec_x   = (const int*)d_in[5];

    const int B  = in_sizes[2];
    const int NR = in_sizes[4];
    const int NT = in_sizes[0] / B;

    float* gcur  = (float*)d_ws;
    float* gprev = gcur + (size_t)B * HH * WW;
    float* outp  = (float*)d_out;

    dim3 grid(NSTRIP, B), block(NTH);
    for (int t0 = 0; t0 < NT; t0 += KT) {
        const int ns = (NT - t0 < KT) ? (NT - t0) : KT;
        wave_chunk<<<grid, block, 0, stream>>>(x, vp, src_y, src_x, rec_y, rec_x,
                                               gcur, gprev, outp, t0, ns, B, NR,
                                               (t0 == 0) ? 1 : 0);
    }
}